// Round 3
// baseline (274.688 us; speedup 1.0000x reference)
//
#include <hip/hip_runtime.h>
#include <math.h>

// B=16 rows, D=2^21 fp32/row. loss = mean_i sqrt(sum_j (out-lab)^2).
// R2 finding: atomics were NOT the problem (identical 99us without them).
// Counters: duration invariant to L3 residency, VALUBusy 3%, VGPR=32.
// Diagnosis: register-starved load scheduling -> per-wave MLP~2 ->
// latency-bound at 4.4 B/cyc/CU. This round: explicit 8-deep load batches
// + 4 accumulators to force high MLP (expect VGPR ~64-88).

constexpr int B = 16;
constexpr int D = 2097152;                       // 2^21
constexpr int THREADS = 256;
constexpr int PAIRS_PER_BATCH = 4;               // float4 pairs loaded back-to-back
constexpr int BATCHES = 2;                       // 8 float4 per thread total (32 floats)
constexpr int FLOATS_PER_BLOCK = THREADS * PAIRS_PER_BATCH * BATCHES * 4;  // 8192
constexpr int BLOCKS_PER_ROW = D / FLOATS_PER_BLOCK;                       // 256
constexpr int GRID = B * BLOCKS_PER_ROW;                                   // 4096

__global__ __launch_bounds__(THREADS)
void sqdiff_partial_kernel(const float4* __restrict__ out,
                           const float4* __restrict__ lab,
                           float* __restrict__ partials) {
    const int row   = blockIdx.x / BLOCKS_PER_ROW;
    const int chunk = blockIdx.x % BLOCKS_PER_ROW;
    const size_t base = (size_t)row * (D / 4)
                      + (size_t)chunk * (THREADS * PAIRS_PER_BATCH * BATCHES)
                      + threadIdx.x;

    float acc0 = 0.0f, acc1 = 0.0f, acc2 = 0.0f, acc3 = 0.0f;

#pragma unroll
    for (int b = 0; b < BATCHES; ++b) {
        float4 o[PAIRS_PER_BATCH];
        float4 l[PAIRS_PER_BATCH];
        // Issue all 8 loads before consuming any: forces MLP=8 in-flight.
#pragma unroll
        for (int i = 0; i < PAIRS_PER_BATCH; ++i)
            o[i] = out[base + (size_t)(b * PAIRS_PER_BATCH + i) * THREADS];
#pragma unroll
        for (int i = 0; i < PAIRS_PER_BATCH; ++i)
            l[i] = lab[base + (size_t)(b * PAIRS_PER_BATCH + i) * THREADS];
#pragma unroll
        for (int i = 0; i < PAIRS_PER_BATCH; ++i) {
            const float dx = o[i].x - l[i].x;
            const float dy = o[i].y - l[i].y;
            const float dz = o[i].z - l[i].z;
            const float dw = o[i].w - l[i].w;
            acc0 = fmaf(dx, dx, acc0);
            acc1 = fmaf(dy, dy, acc1);
            acc2 = fmaf(dz, dz, acc2);
            acc3 = fmaf(dw, dw, acc3);
        }
    }

    float acc = (acc0 + acc1) + (acc2 + acc3);

    // wave-64 tree reduce
#pragma unroll
    for (int off = 32; off > 0; off >>= 1)
        acc += __shfl_down(acc, off, 64);

    __shared__ float smem[THREADS / 64];
    const int lane = threadIdx.x & 63;
    const int wave = threadIdx.x >> 6;
    if (lane == 0) smem[wave] = acc;
    __syncthreads();

    if (threadIdx.x == 0)
        partials[blockIdx.x] = smem[0] + smem[1] + smem[2] + smem[3];
}

// One block, 1024 threads = 16 waves. Wave w reduces row w's 256 partials.
__global__ __launch_bounds__(1024)
void finalize_kernel(const float* __restrict__ partials,
                     float* __restrict__ loss) {
    const int wave = threadIdx.x >> 6;   // row
    const int lane = threadIdx.x & 63;

    float s = 0.0f;
#pragma unroll
    for (int k = 0; k < BLOCKS_PER_ROW / 64; ++k)
        s += partials[wave * BLOCKS_PER_ROW + k * 64 + lane];

#pragma unroll
    for (int off = 32; off > 0; off >>= 1)
        s += __shfl_down(s, off, 64);

    __shared__ float row_dist[B];
    if (lane == 0) row_dist[wave] = sqrtf(s);
    __syncthreads();

    if (wave == 0) {
        float v = (lane < B) ? row_dist[lane] : 0.0f;
#pragma unroll
        for (int off = 32; off > 0; off >>= 1)
            v += __shfl_down(v, off, 64);
        if (lane == 0) loss[0] = v * (1.0f / (float)B);
    }
}

extern "C" void kernel_launch(void* const* d_in, const int* in_sizes, int n_in,
                              void* d_out, int out_size, void* d_ws, size_t ws_size,
                              hipStream_t stream) {
    const float4* out_p = (const float4*)d_in[0];
    const float4* lab_p = (const float4*)d_in[1];
    float* partials = (float*)d_ws;

    sqdiff_partial_kernel<<<GRID, THREADS, 0, stream>>>(out_p, lab_p, partials);
    finalize_kernel<<<1, 1024, 0, stream>>>(partials, (float*)d_out);
}